// Round 4
// baseline (1626.665 us; speedup 1.0000x reference)
//
#include <hip/hip_runtime.h>

// LSTM: SEQ=512, B=64, IN=256, H=512, fp32 in/out; bf16 MFMA compute.
// 4 batch-groups x 16 H-slice blocks (32 hid x 4 gates), persistent, 512 steps.
//
// Round-4 structure: h exchanged as PACKED BF16 via a 4-deep ring in d_ws,
// laid out in the consumer's MFMA fragment order (consumer copies u64s to LDS,
// zero repack). d_out h_seq = plain cached stores, off the critical path.
// Flags = per-slice monotonic step counters (sc0sc1 store / 16-lane ballot
// poll; no RMW, no per-step re-zero). x prefetch issued AFTER the release
// vmcnt(0) so it overlaps the poll. g_lds stride 18 kills the 4-way bank
// conflict on accumulator exchange.

#define T_STEPS 512
#define BATCH   64
#define IN_D    256
#define HID     512
#define NGROUP  4
#define NSLICE  16
#define BLK_B   16
#define BLK_H   32
#define THREADS 512
#define RING    4
#define RING_BYTES 16384            // 16 rows x 512 hid x 2B per group-slot
#define GSTRIDE 288                 // g_lds row-section stride (floats), 16x18

using short8  = __attribute__((ext_vector_type(8))) short;
using float4v = __attribute__((ext_vector_type(4))) float;

#define FRAG_ADDR(f) (((f) << 4) + (((f) >> 4) << 4))   // 16B frag + 16B pad per 16 frags

__device__ __forceinline__ unsigned short f2bf(float f) {
    union { float f; unsigned int i; } v; v.f = f;
    unsigned int r = v.i + 0x7fff + ((v.i >> 16) & 1);
    return (unsigned short)(r >> 16);
}
__device__ __forceinline__ short8 pack8(float4 a, float4 b) {
    short8 s;
    s[0]=(short)f2bf(a.x); s[1]=(short)f2bf(a.y); s[2]=(short)f2bf(a.z); s[3]=(short)f2bf(a.w);
    s[4]=(short)f2bf(b.x); s[5]=(short)f2bf(b.y); s[6]=(short)f2bf(b.z); s[7]=(short)f2bf(b.w);
    return s;
}
__device__ __forceinline__ float sigm(float v) { return 1.0f / (1.0f + __expf(-v)); }
__device__ __forceinline__ float tanh_(float v) { return 2.0f / (1.0f + __expf(-2.0f * v)) - 1.0f; }

__global__ __launch_bounds__(64, 1) void lstm_init_flags(unsigned int* flags) {
    flags[threadIdx.x] = 0u;    // NGROUP*NSLICE = 64 monotonic counters
}

__global__ __launch_bounds__(THREADS, 2) void lstm_persist(
    const float* __restrict__ x,
    const float* __restrict__ h0,
    const float* __restrict__ c0,
    const float* __restrict__ Wf, const float* __restrict__ Wfb,
    const float* __restrict__ Uf, const float* __restrict__ Ufb,
    const float* __restrict__ Wi, const float* __restrict__ Wib,
    const float* __restrict__ Ui, const float* __restrict__ Uib,
    const float* __restrict__ Wo, const float* __restrict__ Wob,
    const float* __restrict__ Uo, const float* __restrict__ Uob,
    const float* __restrict__ Wc, const float* __restrict__ Wcb,
    const float* __restrict__ Uc, const float* __restrict__ Ucb,
    float* out,                 // h_seq (T,B,H) | h (B,H) | c (B,H), fp32
    unsigned char* ws)          // [0,256): flags; [16K, 16K+4*64K): h rings
{
    __shared__ __attribute__((aligned(16))) unsigned char hfrag[17408]; // 1024 frags + pad
    __shared__ __attribute__((aligned(16))) unsigned char xfrag[8704];  // 512 frags + pad
    __shared__ float g_lds[8 * GSTRIDE];                                // gates, stride 18

    const int tid  = threadIdx.x;
    const int lane = tid & 63;
    const int wave = tid >> 6;            // 0..7
    const int gate = wave >> 1;           // 0:f 1:i 2:o 3:c
    const int hlf  = wave & 1;            // 16-hid half of the 32
    const int grp  = blockIdx.x & 3;      // batch group
    const int slc  = blockIdx.x >> 2;     // hid slice
    const int bb   = grp * BLK_B;
    const int hbase= slc * BLK_H;
    const int lm   = lane & 15;
    const int lq   = lane >> 4;
    const int row  = tid >> 5;            // 0..15 (batch within group)
    const int seg  = tid & 31;            // 0..31

    const float* Ug  = (gate == 0) ? Uf : (gate == 1) ? Ui : (gate == 2) ? Uo : Uc;
    const float* Wg  = (gate == 0) ? Wf : (gate == 1) ? Wi : (gate == 2) ? Wo : Wc;
    const float* Wbg = (gate == 0) ? Wfb : (gate == 1) ? Wib : (gate == 2) ? Wob : Wcb;
    const float* Ubg = (gate == 0) ? Ufb : (gate == 1) ? Uib : (gate == 2) ? Uob : Ucb;
    const int ng = hbase + hlf * 16 + lm;   // lane's gate-output row (B-op n)

    // ---- register-resident bf16 weight fragments ----
    short8 ufrag[16];
#pragma unroll
    for (int ks = 0; ks < 16; ++ks) {
        const float* p = Ug + (size_t)ng * HID + ks * 32 + lq * 8;
        ufrag[ks] = pack8(*(const float4*)(p), *(const float4*)(p + 4));
    }
    short8 wfrag[8];
#pragma unroll
    for (int ks = 0; ks < 8; ++ks) {
        const float* p = Wg + (size_t)ng * IN_D + ks * 32 + lq * 8;
        wfrag[ks] = pack8(*(const float4*)(p), *(const float4*)(p + 4));
    }
    const float bias = Wbg[ng] + Ubg[ng];

    float c_reg = c0[(size_t)(bb + row) * HID + hbase + seg];

    // ---- stage h0 (2 frags/thread) and x0 (1 frag/thread) ----
    {
        const float* ph = h0 + (size_t)(bb + row) * HID + seg * 16;
        int f0 = (seg >> 1) * 64 + (seg & 1) * 32 + row;
        *(short8*)(hfrag + FRAG_ADDR(f0))      = pack8(*(const float4*)(ph),     *(const float4*)(ph + 4));
        *(short8*)(hfrag + FRAG_ADDR(f0 + 16)) = pack8(*(const float4*)(ph + 8), *(const float4*)(ph + 12));

        const float* px = x + (size_t)(bb + row) * IN_D + seg * 8;
        int fx = (seg >> 2) * 64 + (seg & 3) * 16 + row;
        *(short8*)(xfrag + FRAG_ADDR(fx)) = pack8(*(const float4*)(px), *(const float4*)(px + 4));
    }
    float4 xn0, xn1;
    {
        const float* px = x + ((size_t)1 * BATCH + bb + row) * IN_D + seg * 8;
        xn0 = *(const float4*)(px); xn1 = *(const float4*)(px + 4);
    }
    __syncthreads();

    // accx = bias + x_0 @ W^T
    float4v accx0 = {bias, bias, bias, bias};
    float4v accx1 = {0.f, 0.f, 0.f, 0.f};
#pragma unroll
    for (int ks = 0; ks < 8; ++ks) {
        short8 a = *(const short8*)(xfrag + FRAG_ADDR(ks * 64 + lane));
        if (ks & 1) accx1 = __builtin_amdgcn_mfma_f32_16x16x32_bf16(a, wfrag[ks], accx1, 0, 0, 0);
        else        accx0 = __builtin_amdgcn_mfma_f32_16x16x32_bf16(a, wfrag[ks], accx0, 0, 0, 0);
    }

    unsigned int* const flagg = (unsigned int*)ws + grp * NSLICE;       // 16 counters
    unsigned char* const ring = ws + 16384 + grp * (RING * RING_BYTES);
    float* const out_h = out + (size_t)T_STEPS * BATCH * HID;
    float* const out_c = out_h + (size_t)BATCH * HID;

    for (int t = 0; t < T_STEPS; ++t) {
        // ---- h-part MFMAs (4 accumulator chains) ----
        float4v a0 = accx0, a1 = accx1;
        float4v a2 = {0.f, 0.f, 0.f, 0.f}, a3 = {0.f, 0.f, 0.f, 0.f};
#pragma unroll
        for (int ks = 0; ks < 16; ++ks) {
            short8 a = *(const short8*)(hfrag + FRAG_ADDR(ks * 64 + lane));
            switch (ks & 3) {
                case 0: a0 = __builtin_amdgcn_mfma_f32_16x16x32_bf16(a, ufrag[ks], a0, 0, 0, 0); break;
                case 1: a1 = __builtin_amdgcn_mfma_f32_16x16x32_bf16(a, ufrag[ks], a1, 0, 0, 0); break;
                case 2: a2 = __builtin_amdgcn_mfma_f32_16x16x32_bf16(a, ufrag[ks], a2, 0, 0, 0); break;
                default:a3 = __builtin_amdgcn_mfma_f32_16x16x32_bf16(a, ufrag[ks], a3, 0, 0, 0); break;
            }
        }
        float4v acc = (a0 + a2) + (a1 + a3);
#pragma unroll
        for (int r = 0; r < 4; ++r)
            g_lds[wave * GSTRIDE + (lq * 4 + r) * 18 + lm] = acc[r];   // 2-way banks: free
        __syncthreads();   // A: gates visible; hfrag/xfrag MFMA reads done

        // ---- pointwise (fp32, c in register) ----
        unsigned char* const slot = ring + (size_t)(t & (RING - 1)) * RING_BYTES;
        float hv;
        {
            int hf2 = seg >> 4, nn = seg & 15;
            float fpre = g_lds[(0 * 2 + hf2) * GSTRIDE + row * 18 + nn];
            float ipre = g_lds[(1 * 2 + hf2) * GSTRIDE + row * 18 + nn];
            float opre = g_lds[(2 * 2 + hf2) * GSTRIDE + row * 18 + nn];
            float gpre = g_lds[(3 * 2 + hf2) * GSTRIDE + row * 18 + nn];
            float fv = sigm(fpre), iv = sigm(ipre), ov = sigm(opre);
            float gv = tanh_(gpre);
            c_reg = fv * c_reg + iv * gv;
            hv = ov * tanh_(c_reg);
        }
        // bf16-pair pack; even lane stores one u32 write-through to the ring,
        // pre-arranged in consumer fragment order: frag(ks=slc, lq=n>>3, lm=row)
        {
            unsigned short h16 = f2bf(hv);
            unsigned int partner = ((unsigned int)__shfl_xor((int)h16, 1)) & 0xffffu;
            if ((seg & 1) == 0) {
                unsigned int word = ((unsigned int)h16) | (partner << 16);
                unsigned int* dst = (unsigned int*)(slot + slc * 1024 + (seg >> 3) * 256
                                                    + row * 16 + (seg & 7) * 2);
                __hip_atomic_store(dst, word, __ATOMIC_RELAXED, __HIP_MEMORY_SCOPE_AGENT);
            }
        }
        // h_seq output: plain cached store, OFF the critical path (never read)
        out[((size_t)t * BATCH + bb + row) * HID + hbase + seg] = hv;
        if (t == T_STEPS - 1) {
            out_h[(size_t)(bb + row) * HID + hbase + seg] = hv;
            out_c[(size_t)(bb + row) * HID + hbase + seg] = c_reg;
        }

        // ---- stage x_{t+1} frag from regs (LDS; not counted by vmcnt) ----
        if (t + 1 < T_STEPS) {
            int fx = (seg >> 2) * 64 + (seg & 3) * 16 + row;
            *(short8*)(xfrag + FRAG_ADDR(fx)) = pack8(xn0, xn1);
        }

        asm volatile("s_waitcnt vmcnt(0)" ::: "memory");  // ring stores acked at MALL

        // x prefetch t+2: AFTER the drain -> flies during flag/poll window
        if (t + 1 < T_STEPS) {
            int tn = (t + 2 < T_STEPS) ? (t + 2) : (T_STEPS - 1);
            const float* px = x + ((size_t)tn * BATCH + bb + row) * IN_D + seg * 8;
            xn0 = *(const float4*)(px); xn1 = *(const float4*)(px + 4);
        }
        __syncthreads();   // A2: all waves' ring stores acked; xfrag(t+1) staged

        if (t + 1 < T_STEPS) {
            if (tid == 0)   // monotonic per-slice counter: no RMW, no re-zero
                __hip_atomic_store(&flagg[slc], (unsigned)(t + 1),
                                   __ATOMIC_RELAXED, __HIP_MEMORY_SCOPE_AGENT);

            // accx for t+1 — overlaps flag propagation
            accx0 = (float4v){bias, bias, bias, bias};
            accx1 = (float4v){0.f, 0.f, 0.f, 0.f};
#pragma unroll
            for (int ks = 0; ks < 8; ++ks) {
                short8 a = *(const short8*)(xfrag + FRAG_ADDR(ks * 64 + lane));
                if (ks & 1) accx1 = __builtin_amdgcn_mfma_f32_16x16x32_bf16(a, wfrag[ks], accx1, 0, 0, 0);
                else        accx0 = __builtin_amdgcn_mfma_f32_16x16x32_bf16(a, wfrag[ks], accx0, 0, 0, 0);
            }

            if (wave == 0) {
                bool need = lane < NSLICE;
                while (true) {
                    unsigned v = need ? __hip_atomic_load(&flagg[lane], __ATOMIC_RELAXED,
                                                          __HIP_MEMORY_SCOPE_AGENT)
                                      : 0xffffffffu;
                    if (__ballot(need && (v < (unsigned)(t + 1))) == 0ull) break;
                }
            }
            __syncthreads();   // B: h_t published by all 16 producers

            // ---- ring -> LDS: 32B/thread, already bf16 in frag order ----
            {
                const unsigned long long* src =
                    (const unsigned long long*)(slot) + (size_t)tid * 4;
                unsigned long long d0 = __hip_atomic_load(src + 0, __ATOMIC_RELAXED, __HIP_MEMORY_SCOPE_AGENT);
                unsigned long long d1 = __hip_atomic_load(src + 1, __ATOMIC_RELAXED, __HIP_MEMORY_SCOPE_AGENT);
                unsigned long long d2 = __hip_atomic_load(src + 2, __ATOMIC_RELAXED, __HIP_MEMORY_SCOPE_AGENT);
                unsigned long long d3 = __hip_atomic_load(src + 3, __ATOMIC_RELAXED, __HIP_MEMORY_SCOPE_AGENT);
                unsigned char* dst = hfrag + 32 * tid + 16 * (tid >> 3);  // FRAG_ADDR(2*tid)
                *(unsigned long long*)(dst)      = d0;
                *(unsigned long long*)(dst + 8)  = d1;
                *(unsigned long long*)(dst + 16) = d2;
                *(unsigned long long*)(dst + 24) = d3;
            }
            __syncthreads();   // C: hfrag ready for next step
        }
    }
}

extern "C" void kernel_launch(void* const* d_in, const int* in_sizes, int n_in,
                              void* d_out, int out_size, void* d_ws, size_t ws_size,
                              hipStream_t stream) {
    (void)in_sizes; (void)n_in; (void)out_size; (void)ws_size;
    const float* x   = (const float*)d_in[0];
    const float* h0  = (const float*)d_in[1];
    const float* c0  = (const float*)d_in[2];
    const float* Wf  = (const float*)d_in[3];
    const float* Wfb = (const float*)d_in[4];
    const float* Uf  = (const float*)d_in[5];
    const float* Ufb = (const float*)d_in[6];
    const float* Wi  = (const float*)d_in[7];
    const float* Wib = (const float*)d_in[8];
    const float* Ui  = (const float*)d_in[9];
    const float* Uib = (const float*)d_in[10];
    const float* Wo  = (const float*)d_in[11];
    const float* Wob = (const float*)d_in[12];
    const float* Uo  = (const float*)d_in[13];
    const float* Uob = (const float*)d_in[14];
    const float* Wc  = (const float*)d_in[15];
    const float* Wcb = (const float*)d_in[16];
    const float* Uc  = (const float*)d_in[17];
    const float* Ucb = (const float*)d_in[18];

    lstm_init_flags<<<1, 64, 0, stream>>>((unsigned int*)d_ws);
    lstm_persist<<<NGROUP * NSLICE, THREADS, 0, stream>>>(
        x, h0, c0,
        Wf, Wfb, Uf, Ufb, Wi, Wib, Ui, Uib,
        Wo, Wob, Uo, Uob, Wc, Wcb, Uc, Ucb,
        (float*)d_out, (unsigned char*)d_ws);
}